// Round 7
// baseline (325.869 us; speedup 1.0000x reference)
//
#include <hip/hip_runtime.h>

// GRUCell fused kernel for MI355X (gfx950), round 7.
// B=65536, I=128, H=256, CAT=384. f16 MFMA 16x16x32.
// R6 -> R7: kill the LDS weight pipeline entirely. Prep writes weights in
// FRAGMENT-MAJOR order (1KB per (matrix,kchunk,coltile) block, exact MFMA
// B-fragment lane layout), so each B-fragment is ONE coalesced
// global_load_dwordx4 (base + lane*16) from L2-resident data. Main loops have
// NO barriers / NO vmcnt ledger; compiler pipelines the 8 independent loads
// per k-step under 16 MFMAs. LDS = 48KB act only -> 3 blocks/CU, 24 waves/CU.

#define BATCH 65536
#define ISZ   128
#define HSZ   256
#define CAT   384
#define BM    64
#define NT    512
#define ROWB  768              // act row bytes (384 f16: x 256B + h 512B)
#define ACT_B (BM * ROWB)      // 49152
#define MSTR  196608           // bytes per matrix in fragment-major ws (192KB)

using half8   = __attribute__((ext_vector_type(8))) _Float16;
using floatx4 = __attribute__((ext_vector_type(4))) float;

#define MFMA __builtin_amdgcn_mfma_f32_16x16x32_f16

__device__ __forceinline__ float hsig(float x) {
    return fminf(fmaxf(x * (1.0f / 6.0f) + 0.5f, 0.0f), 1.0f);
}
__device__ __forceinline__ float htanh(float x) {
    return fminf(fmaxf(x, -1.0f), 1.0f);
}
__device__ __forceinline__ half8 cvt8(float4 v0, float4 v1) {
    half8 h;
    h[0] = (_Float16)v0.x; h[1] = (_Float16)v0.y;
    h[2] = (_Float16)v0.z; h[3] = (_Float16)v0.w;
    h[4] = (_Float16)v1.x; h[5] = (_Float16)v1.y;
    h[6] = (_Float16)v1.z; h[7] = (_Float16)v1.w;
    return h;
}

// ---- weight prep: f32 [256x384] row-major -> f16 FRAGMENT-MAJOR in d_ws ----
// Fragment block (m, kk, c) at byte offset (m*192 + kk*16 + c)*1024.
// Within a block, lane l's 16B: col = c*16 + (l&15), k = kk*32 + (l>>4)*8 .. +8
// (identical to the wread layout validated in R1-R6).
__global__ __launch_bounds__(256) void prep_weights(
    const float* __restrict__ Wz, const float* __restrict__ Wr,
    const float* __restrict__ Wh, unsigned char* __restrict__ ws)
{
    const int m  = blockIdx.y;          // matrix
    const int kk = blockIdx.x;          // k-chunk 0..11
    const float* src = (m == 0) ? Wz : (m == 1) ? Wr : Wh;
    const int t = threadIdx.x;
    const int l = t & 63;
    #pragma unroll
    for (int c4 = 0; c4 < 4; ++c4) {
        const int c   = c4 * 4 + (t >> 6);          // col-tile 0..15
        const int col = c * 16 + (l & 15);
        const int k0  = kk * 32 + (l >> 4) * 8;
        float4 v0 = *(const float4*)(src + col * CAT + k0);
        float4 v1 = *(const float4*)(src + col * CAT + k0 + 4);
        *(half8*)(ws + (size_t)(m * 192 + kk * 16 + c) * 1024 + l * 16) =
            cvt8(v0, v1);
    }
}

__global__ __launch_bounds__(NT, 6) void gru_kernel(
    const float* __restrict__ x, const float* __restrict__ h_prev,
    const float* __restrict__ b_z, const float* __restrict__ b_r,
    const float* __restrict__ b_h, const unsigned char* __restrict__ wsF,
    float* __restrict__ out)
{
    __shared__ __align__(16) unsigned char act[ACT_B];   // 48 KiB

    const int t    = threadIdx.x;
    const int lane = t & 63;
    const int w    = t >> 6;
    const int mg   = w >> 2;        // rows mg*32 .. +31
    const int ng   = w & 3;         // cols ng*64 .. +63
    const int lr   = lane & 15;
    const int lk   = lane >> 4;
    const int row0 = blockIdx.x * BM;

    // per-wave fragment base: col-tiles ng*4 .. ng*4+3, this lane's 16B
    const unsigned char* fb = wsF + (size_t)(ng * 4) * 1024 + lane * 16;

    // biases folded into accumulator init; b_h held for phase 2
    float bhv[4];
    floatx4 accz[2][4], accr[2][4];
    #pragma unroll
    for (int j = 0; j < 4; ++j) {
        const int col = ng * 64 + j * 16 + lr;
        const float vz = b_z[col];
        const float vr = b_r[col];
        bhv[j] = b_h[col];
        floatx4 tz = {vz, vz, vz, vz};
        floatx4 tr = {vr, vr, vr, vr};
        accz[0][j] = tz; accz[1][j] = tz;
        accr[0][j] = tr; accr[1][j] = tr;
    }

    // ---- stage act: x (64x128) + h (64x256), f32 -> f16, row-XOR swizzled ----
    for (int c = t; c < BM * 16; c += NT) {
        int row = c >> 4, kc = c & 15;
        const float* g = x + (size_t)(row0 + row) * ISZ + kc * 8;
        float4 v0 = *(const float4*)g;
        float4 v1 = *(const float4*)(g + 4);
        *(half8*)(act + row * ROWB + ((kc * 16) ^ ((row & 7) << 4))) = cvt8(v0, v1);
    }
    for (int c = t; c < BM * 32; c += NT) {
        int row = c >> 5, kc = c & 31;
        const float* g = h_prev + (size_t)(row0 + row) * HSZ + kc * 8;
        float4 v0 = *(const float4*)g;
        float4 v1 = *(const float4*)(g + 4);
        *(half8*)(act + row * ROWB + ((256 + kc * 16) ^ ((row & 7) << 4))) = cvt8(v0, v1);
    }
    __syncthreads();   // barrier #1: act staged

    const int rowA = mg * 32 + lr;
    const int asw  = (lr & 7) << 4;   // rowA&7 == (rowA+16)&7 == lr&7

    // ---- phase 1: z,r pre-activations. No barriers; loads pipeline freely. ----
    #pragma unroll 2
    for (int kk = 0; kk < 12; ++kk) {
        half8 a0 = *(const half8*)(act + rowA * ROWB +
                                   ((kk * 64 + lk * 16) ^ asw));
        half8 a1 = *(const half8*)(act + (rowA + 16) * ROWB +
                                   ((kk * 64 + lk * 16) ^ asw));
        const unsigned char* pk = fb + kk * 16384;
        half8 bz[4], br[4];
        #pragma unroll
        for (int j = 0; j < 4; ++j) bz[j] = *(const half8*)(pk + j * 1024);
        #pragma unroll
        for (int j = 0; j < 4; ++j) br[j] = *(const half8*)(pk + MSTR + j * 1024);
        #pragma unroll
        for (int j = 0; j < 4; ++j) {
            accz[0][j] = MFMA(a0, bz[j], accz[0][j], 0, 0, 0);
            accz[1][j] = MFMA(a1, bz[j], accz[1][j], 0, 0, 0);
        }
        #pragma unroll
        for (int j = 0; j < 4; ++j) {
            accr[0][j] = MFMA(a0, br[j], accr[0][j], 0, 0, 0);
            accr[1][j] = MFMA(a1, br[j], accr[1][j], 0, 0, 0);
        }
    }

    __syncthreads();   // barrier #2: all phase-1 act reads done before overwrite

    // ---- rescale: z = hsig(acc); r*h overwrites act h-region in place ----
    #pragma unroll
    for (int f = 0; f < 2; ++f) {
        #pragma unroll
        for (int j = 0; j < 4; ++j) {
            #pragma unroll
            for (int q = 0; q < 4; ++q) {
                const int row = mg * 32 + f * 16 + lk * 4 + q;  // C/D row=(l>>4)*4+q
                const int col = ng * 64 + j * 16 + lr;          //     col=l&15
                accz[f][j][q] = hsig(accz[f][j][q]);            // bias pre-added
                float rr = hsig(accr[f][j][q]);
                _Float16* hp = (_Float16*)(act + row * ROWB +
                                           ((256 + col * 2) ^ ((row & 7) << 4)));
                float hv = (float)hp[0];
                hp[0] = (_Float16)(rr * hv);
            }
        }
    }
    __syncthreads();   // barrier #3: r*h visible to all waves

    // ---- phase 2: h_tilde pre-activation ----
    floatx4 acch[2][4];
    #pragma unroll
    for (int j = 0; j < 4; ++j) {
        floatx4 th = {bhv[j], bhv[j], bhv[j], bhv[j]};
        acch[0][j] = th; acch[1][j] = th;
    }
    #pragma unroll 2
    for (int kk = 0; kk < 12; ++kk) {
        half8 a0 = *(const half8*)(act + rowA * ROWB +
                                   ((kk * 64 + lk * 16) ^ asw));
        half8 a1 = *(const half8*)(act + (rowA + 16) * ROWB +
                                   ((kk * 64 + lk * 16) ^ asw));
        const unsigned char* pk = fb + 2 * MSTR + kk * 16384;
        half8 bh[4];
        #pragma unroll
        for (int j = 0; j < 4; ++j) bh[j] = *(const half8*)(pk + j * 1024);
        #pragma unroll
        for (int j = 0; j < 4; ++j) {
            acch[0][j] = MFMA(a0, bh[j], acch[0][j], 0, 0, 0);
            acch[1][j] = MFMA(a1, bh[j], acch[1][j], 0, 0, 0);
        }
    }

    // ---- epilogue: h_next = z*h + (1-z)*hardtanh(.) ----
    #pragma unroll
    for (int f = 0; f < 2; ++f) {
        #pragma unroll
        for (int j = 0; j < 4; ++j) {
            #pragma unroll
            for (int q = 0; q < 4; ++q) {
                const int row = mg * 32 + f * 16 + lk * 4 + q;
                const int col = ng * 64 + j * 16 + lr;
                float ht = htanh(acch[f][j][q]);               // bias pre-added
                float zz = accz[f][j][q];
                float hv = h_prev[(size_t)(row0 + row) * HSZ + col];
                out[(size_t)(row0 + row) * HSZ + col] = zz * hv + (1.0f - zz) * ht;
            }
        }
    }
}

extern "C" void kernel_launch(void* const* d_in, const int* in_sizes, int n_in,
                              void* d_out, int out_size, void* d_ws, size_t ws_size,
                              hipStream_t stream) {
    const float* x  = (const float*)d_in[0];
    const float* h  = (const float*)d_in[1];
    const float* Wz = (const float*)d_in[2];
    const float* bz = (const float*)d_in[3];
    const float* Wr = (const float*)d_in[4];
    const float* br = (const float*)d_in[5];
    const float* Wh = (const float*)d_in[6];
    const float* bh = (const float*)d_in[7];
    unsigned char* wf = (unsigned char*)d_ws;   // 576 KiB fragment-major weights

    prep_weights<<<dim3(12, 3), 256, 0, stream>>>(Wz, Wr, Wh, wf);
    gru_kernel<<<dim3(BATCH / BM), NT, 0, stream>>>(
        x, h, bz, br, bh, wf, (float*)d_out);
}

// Round 8
// 204.612 us; speedup vs baseline: 1.5926x; 1.5926x over previous
//
#include <hip/hip_runtime.h>

// GRUCell fused kernel for MI355X (gfx950), round 8.
// B=65536, I=128, H=256, CAT=384. f16 MFMA 16x16x32.
// R7 -> R8: R7's launch_bounds(512,6) capped the unified VGPR/AGPR budget at
// ~85 regs/wave; the ~115-reg working set (acc + fragments) spilled to
// scratch -> +314MB writes, +90MB reads, MfmaUtil 6%. Single change: bound
// min-waves/EU at 4 (budget 128, 2 blocks/CU, 16 waves/CU) so nothing spills.
// Structure unchanged: fragment-major weights read directly from L2 (one
// coalesced dwordx4 per B-fragment), no in-loop barriers, LDS = 48KB act.

#define BATCH 65536
#define ISZ   128
#define HSZ   256
#define CAT   384
#define BM    64
#define NT    512
#define ROWB  768              // act row bytes (384 f16: x 256B + h 512B)
#define ACT_B (BM * ROWB)      // 49152
#define MSTR  196608           // bytes per matrix in fragment-major ws (192KB)

using half8   = __attribute__((ext_vector_type(8))) _Float16;
using floatx4 = __attribute__((ext_vector_type(4))) float;

#define MFMA __builtin_amdgcn_mfma_f32_16x16x32_f16

__device__ __forceinline__ float hsig(float x) {
    return fminf(fmaxf(x * (1.0f / 6.0f) + 0.5f, 0.0f), 1.0f);
}
__device__ __forceinline__ float htanh(float x) {
    return fminf(fmaxf(x, -1.0f), 1.0f);
}
__device__ __forceinline__ half8 cvt8(float4 v0, float4 v1) {
    half8 h;
    h[0] = (_Float16)v0.x; h[1] = (_Float16)v0.y;
    h[2] = (_Float16)v0.z; h[3] = (_Float16)v0.w;
    h[4] = (_Float16)v1.x; h[5] = (_Float16)v1.y;
    h[6] = (_Float16)v1.z; h[7] = (_Float16)v1.w;
    return h;
}

// ---- weight prep: f32 [256x384] row-major -> f16 FRAGMENT-MAJOR in d_ws ----
// Fragment block (m, kk, c) at byte offset (m*192 + kk*16 + c)*1024.
// Within a block, lane l's 16B: col = c*16 + (l&15), k = kk*32 + (l>>4)*8 .. +8
// (identical to the wread layout validated in R1-R6).
__global__ __launch_bounds__(256) void prep_weights(
    const float* __restrict__ Wz, const float* __restrict__ Wr,
    const float* __restrict__ Wh, unsigned char* __restrict__ ws)
{
    const int m  = blockIdx.y;          // matrix
    const int kk = blockIdx.x;          // k-chunk 0..11
    const float* src = (m == 0) ? Wz : (m == 1) ? Wr : Wh;
    const int t = threadIdx.x;
    const int l = t & 63;
    #pragma unroll
    for (int c4 = 0; c4 < 4; ++c4) {
        const int c   = c4 * 4 + (t >> 6);          // col-tile 0..15
        const int col = c * 16 + (l & 15);
        const int k0  = kk * 32 + (l >> 4) * 8;
        float4 v0 = *(const float4*)(src + col * CAT + k0);
        float4 v1 = *(const float4*)(src + col * CAT + k0 + 4);
        *(half8*)(ws + (size_t)(m * 192 + kk * 16 + c) * 1024 + l * 16) =
            cvt8(v0, v1);
    }
}

__global__ __launch_bounds__(NT, 4) void gru_kernel(
    const float* __restrict__ x, const float* __restrict__ h_prev,
    const float* __restrict__ b_z, const float* __restrict__ b_r,
    const float* __restrict__ b_h, const unsigned char* __restrict__ wsF,
    float* __restrict__ out)
{
    __shared__ __align__(16) unsigned char act[ACT_B];   // 48 KiB

    const int t    = threadIdx.x;
    const int lane = t & 63;
    const int w    = t >> 6;
    const int mg   = w >> 2;        // rows mg*32 .. +31
    const int ng   = w & 3;         // cols ng*64 .. +63
    const int lr   = lane & 15;
    const int lk   = lane >> 4;
    const int row0 = blockIdx.x * BM;

    // per-wave fragment base: col-tiles ng*4 .. ng*4+3, this lane's 16B
    const unsigned char* fb = wsF + (size_t)(ng * 4) * 1024 + lane * 16;

    // biases folded into accumulator init; b_h held for phase 2
    float bhv[4];
    floatx4 accz[2][4], accr[2][4];
    #pragma unroll
    for (int j = 0; j < 4; ++j) {
        const int col = ng * 64 + j * 16 + lr;
        const float vz = b_z[col];
        const float vr = b_r[col];
        bhv[j] = b_h[col];
        floatx4 tz = {vz, vz, vz, vz};
        floatx4 tr = {vr, vr, vr, vr};
        accz[0][j] = tz; accz[1][j] = tz;
        accr[0][j] = tr; accr[1][j] = tr;
    }

    // ---- stage act: x (64x128) + h (64x256), f32 -> f16, row-XOR swizzled ----
    for (int c = t; c < BM * 16; c += NT) {
        int row = c >> 4, kc = c & 15;
        const float* g = x + (size_t)(row0 + row) * ISZ + kc * 8;
        float4 v0 = *(const float4*)g;
        float4 v1 = *(const float4*)(g + 4);
        *(half8*)(act + row * ROWB + ((kc * 16) ^ ((row & 7) << 4))) = cvt8(v0, v1);
    }
    for (int c = t; c < BM * 32; c += NT) {
        int row = c >> 5, kc = c & 31;
        const float* g = h_prev + (size_t)(row0 + row) * HSZ + kc * 8;
        float4 v0 = *(const float4*)g;
        float4 v1 = *(const float4*)(g + 4);
        *(half8*)(act + row * ROWB + ((256 + kc * 16) ^ ((row & 7) << 4))) = cvt8(v0, v1);
    }
    __syncthreads();   // barrier #1: act staged

    const int rowA = mg * 32 + lr;
    const int asw  = (lr & 7) << 4;   // rowA&7 == (rowA+16)&7 == lr&7

    // ---- phase 1: z,r pre-activations. No barriers; loads pipeline freely. ----
    #pragma unroll 2
    for (int kk = 0; kk < 12; ++kk) {
        half8 a0 = *(const half8*)(act + rowA * ROWB +
                                   ((kk * 64 + lk * 16) ^ asw));
        half8 a1 = *(const half8*)(act + (rowA + 16) * ROWB +
                                   ((kk * 64 + lk * 16) ^ asw));
        const unsigned char* pk = fb + kk * 16384;
        half8 bz[4], br[4];
        #pragma unroll
        for (int j = 0; j < 4; ++j) bz[j] = *(const half8*)(pk + j * 1024);
        #pragma unroll
        for (int j = 0; j < 4; ++j) br[j] = *(const half8*)(pk + MSTR + j * 1024);
        #pragma unroll
        for (int j = 0; j < 4; ++j) {
            accz[0][j] = MFMA(a0, bz[j], accz[0][j], 0, 0, 0);
            accz[1][j] = MFMA(a1, bz[j], accz[1][j], 0, 0, 0);
        }
        #pragma unroll
        for (int j = 0; j < 4; ++j) {
            accr[0][j] = MFMA(a0, br[j], accr[0][j], 0, 0, 0);
            accr[1][j] = MFMA(a1, br[j], accr[1][j], 0, 0, 0);
        }
    }

    __syncthreads();   // barrier #2: all phase-1 act reads done before overwrite

    // ---- rescale: z = hsig(acc); r*h overwrites act h-region in place ----
    #pragma unroll
    for (int f = 0; f < 2; ++f) {
        #pragma unroll
        for (int j = 0; j < 4; ++j) {
            #pragma unroll
            for (int q = 0; q < 4; ++q) {
                const int row = mg * 32 + f * 16 + lk * 4 + q;  // C/D row=(l>>4)*4+q
                const int col = ng * 64 + j * 16 + lr;          //     col=l&15
                accz[f][j][q] = hsig(accz[f][j][q]);            // bias pre-added
                float rr = hsig(accr[f][j][q]);
                _Float16* hp = (_Float16*)(act + row * ROWB +
                                           ((256 + col * 2) ^ ((row & 7) << 4)));
                float hv = (float)hp[0];
                hp[0] = (_Float16)(rr * hv);
            }
        }
    }
    __syncthreads();   // barrier #3: r*h visible to all waves

    // ---- phase 2: h_tilde pre-activation ----
    floatx4 acch[2][4];
    #pragma unroll
    for (int j = 0; j < 4; ++j) {
        floatx4 th = {bhv[j], bhv[j], bhv[j], bhv[j]};
        acch[0][j] = th; acch[1][j] = th;
    }
    #pragma unroll 2
    for (int kk = 0; kk < 12; ++kk) {
        half8 a0 = *(const half8*)(act + rowA * ROWB +
                                   ((kk * 64 + lk * 16) ^ asw));
        half8 a1 = *(const half8*)(act + (rowA + 16) * ROWB +
                                   ((kk * 64 + lk * 16) ^ asw));
        const unsigned char* pk = fb + 2 * MSTR + kk * 16384;
        half8 bh[4];
        #pragma unroll
        for (int j = 0; j < 4; ++j) bh[j] = *(const half8*)(pk + j * 1024);
        #pragma unroll
        for (int j = 0; j < 4; ++j) {
            acch[0][j] = MFMA(a0, bh[j], acch[0][j], 0, 0, 0);
            acch[1][j] = MFMA(a1, bh[j], acch[1][j], 0, 0, 0);
        }
    }

    // ---- epilogue: h_next = z*h + (1-z)*hardtanh(.) ----
    #pragma unroll
    for (int f = 0; f < 2; ++f) {
        #pragma unroll
        for (int j = 0; j < 4; ++j) {
            #pragma unroll
            for (int q = 0; q < 4; ++q) {
                const int row = mg * 32 + f * 16 + lk * 4 + q;
                const int col = ng * 64 + j * 16 + lr;
                float ht = htanh(acch[f][j][q]);               // bias pre-added
                float zz = accz[f][j][q];
                float hv = h_prev[(size_t)(row0 + row) * HSZ + col];
                out[(size_t)(row0 + row) * HSZ + col] = zz * hv + (1.0f - zz) * ht;
            }
        }
    }
}

extern "C" void kernel_launch(void* const* d_in, const int* in_sizes, int n_in,
                              void* d_out, int out_size, void* d_ws, size_t ws_size,
                              hipStream_t stream) {
    const float* x  = (const float*)d_in[0];
    const float* h  = (const float*)d_in[1];
    const float* Wz = (const float*)d_in[2];
    const float* bz = (const float*)d_in[3];
    const float* Wr = (const float*)d_in[4];
    const float* br = (const float*)d_in[5];
    const float* Wh = (const float*)d_in[6];
    const float* bh = (const float*)d_in[7];
    unsigned char* wf = (unsigned char*)d_ws;   // 576 KiB fragment-major weights

    prep_weights<<<dim3(12, 3), 256, 0, stream>>>(Wz, Wr, Wh, wf);
    gru_kernel<<<dim3(BATCH / BM), NT, 0, stream>>>(
        x, h, bz, br, bh, wf, (float*)d_out);
}